// Round 1
// 170.872 us; speedup vs baseline: 1.1994x; 1.1994x over previous
//
#include <hip/hip_runtime.h>

#define NN 4096
#define MM 8192
#define GG 8
#define HH 128
#define NDD 16
#define EE 131072
#define CBLK 64            // cond partial blocks
#define COBJ (MM / CBLK)   // 128 objects per cond block
#define HBLK 16            // deg-histogram blocks
#define HEDGE (EE / HBLK)  // 8192 edges per hist block
#define WBLK 8             // W1p gemm blocks (2 rows each)

typedef float nt_f4 __attribute__((ext_vector_type(4)));

// ============ K1 front: cond partials (0..63) | deg LDS-hist (64..79) | W1p (80..87) ============
__global__ __launch_bounds__(256) void k_front(
    const float* __restrict__ obj_x, const float* __restrict__ obj_pos,
    const int* __restrict__ nuc, const int* __restrict__ central,
    const int* __restrict__ backbone, const int* __restrict__ obj_batch,
    const int* __restrict__ e_dst, int* __restrict__ phist,
    float* __restrict__ partial, float* __restrict__ pcnt,
    const float* __restrict__ Wn, const float* __restrict__ Wc1,
    float* __restrict__ W1p) {
    int b = blockIdx.x, t = threadIdx.x;
    if (b < CBLK) {
        // cond: pool 16-dim inputs. d = t&15, oi = t>>4 (16 objs parallel, 8 passes)
        __shared__ float ls[GG * NDD];
        __shared__ float lc[GG];
        if (t < GG * NDD) ls[t] = 0.f;
        if (t < GG) lc[t] = 0.f;
        __syncthreads();
        int d = t & 15, oi = t >> 4;
        int base = b * COBJ;
#pragma unroll
        for (int pass = 0; pass < COBJ / 16; pass++) {
            int o = base + pass * 16 + oi;
            int nv = nuc[o];
            bool isb = (backbone[o] == 0);
            bool cond = (nv == 0) || ((central[o] != 0) && isb) || ((nv == 2) && isb);
            if (cond) {
                float v = (d < 13) ? obj_x[o * 13 + d] : obj_pos[o * 3 + (d - 13)];
                int g = obj_batch[o];
                atomicAdd(&ls[g * NDD + d], v);
                if (d == 0) atomicAdd(&lc[g], 1.f);
            }
        }
        __syncthreads();
        if (t < GG * NDD) partial[b * (GG * NDD) + t] = ls[t];
        if (t < GG) pcnt[b * GG + t] = lc[t];
        return;
    }
    if (b < CBLK + HBLK) {
        // degree histogram for edge chunk hb (LDS atomics, partial written out)
        int hb = b - CBLK;
        __shared__ int hist[NN];
        for (int i = t; i < NN; i += 256) hist[i] = 0;
        __syncthreads();
        const int4* ed4 = ((const int4*)e_dst) + hb * (HEDGE / 4);
        for (int i = t; i < HEDGE / 4; i += 256) {
            int4 d4 = ed4[i];
            atomicAdd(&hist[d4.x], 1);
            atomicAdd(&hist[d4.y], 1);
            atomicAdd(&hist[d4.z], 1);
            atomicAdd(&hist[d4.w], 1);
        }
        __syncthreads();
        int4* ph4 = (int4*)(phist + hb * NN);
        for (int i = t; i < NN / 4; i += 256) ph4[i] = ((int4*)hist)[i];
        return;
    }
    // W1'[a][j] = sum_k Wn[a][k] * Wc1[k][j] -- 8 blocks, 2 rows each
    int wb = b - (CBLK + HBLK);
    int j = t & 127, a0 = t >> 7;
    int a = wb * 2 + a0;
    float acc = 0.f;
    for (int k = 0; k < HH; k++) acc += Wn[a * HH + k] * Wc1[k * HH + j];
    W1p[a * HH + j] = acc;
}

// ============ K2 mid: c1 per-graph (0..7) | scan (8) | xw1_partial (9..136) ============
__global__ __launch_bounds__(1024) void k_mid(
    const int* __restrict__ timestep, const float* __restrict__ partial,
    const float* __restrict__ pcnt, const float* __restrict__ Wn,
    const float* __restrict__ bn, const float* __restrict__ Wt,
    const float* __restrict__ bt, const float* __restrict__ Wc,
    const float* __restrict__ bc, const float* __restrict__ Wc1,
    float* __restrict__ c1, const int* __restrict__ phist,
    int* __restrict__ row_ptr, int* __restrict__ cursor,
    float* __restrict__ dinv, const float* __restrict__ x,
    const float* __restrict__ W1p, float* __restrict__ xw) {
    int b = blockIdx.x, t = threadIdx.x;
    if (b < GG) {
        // ---- c1[g] = (bn + time_h[g] + cond_h[g]) @ Wc1, one block per graph g ----
        int g = b;
        __shared__ float s16[NDD];
        __shared__ float te[HH];
        __shared__ float pool[HH];
        __shared__ float v2[HH];
        __shared__ float vpart[8][HH];
        __shared__ float cinv;
        int j = t & 127, kq = t >> 7;
        if (t < HH) {
            // timestep embedding
            float tv = (float)timestep[g];
            float val;
            if (t < 64) {
                float f = expf(-logf(10000.f) * (float)t / 64.f);
                val = cosf(tv * f);
            } else {
                float f = expf(-logf(10000.f) * (float)(t - 64) / 64.f);
                val = sinf(tv * f);
            }
            te[t] = val;
        } else if (t < HH + NDD) {
            int d = t - HH;
            float s = 0.f;
            for (int q = 0; q < CBLK; q++) s += partial[q * (GG * NDD) + g * NDD + d];
            s16[d] = s;
        } else if (t == HH + NDD) {
            float c = 0.f;
            for (int q = 0; q < CBLK; q++) c += pcnt[q * GG + g];
            cinv = 1.f / fmaxf(c, 1.f);
        }
        __syncthreads();
        if (t < HH) {
            float p = bn[t];
#pragma unroll
            for (int d = 0; d < NDD; d++) p += s16[d] * cinv * Wn[d * HH + t];
            pool[t] = p;
        }
        __syncthreads();
        // v2 = bt+bc+bn + te@Wt + pool@Wc, k-split over kq
        float acc = 0.f;
#pragma unroll 4
        for (int k = kq * 16; k < kq * 16 + 16; k++)
            acc += te[k] * Wt[k * HH + j] + pool[k] * Wc[k * HH + j];
        vpart[kq][j] = acc;
        __syncthreads();
        if (t < HH) {
            float v = bt[t] + bc[t] + bn[t];
#pragma unroll
            for (int q = 0; q < 8; q++) v += vpart[q][t];
            v2[t] = v;
        }
        __syncthreads();
        acc = 0.f;
#pragma unroll 4
        for (int k = kq * 16; k < kq * 16 + 16; k++) acc += v2[k] * Wc1[k * HH + j];
        __syncthreads();  // vpart reuse
        vpart[kq][j] = acc;
        __syncthreads();
        if (t < HH) {
            float c = 0.f;
#pragma unroll
            for (int q = 0; q < 8; q++) c += vpart[q][t];
            c1[g * HH + t] = c;
        }
    } else if (b == GG) {
        // ---- scan: deg = sum of 16 hist partials, then exclusive scan ----
        __shared__ int aux[1024];
        int4 d4 = {0, 0, 0, 0};
        const int4* ph4 = (const int4*)phist;
#pragma unroll
        for (int h = 0; h < HBLK; h++) {
            int4 v = ph4[h * (NN / 4) + t];
            d4.x += v.x; d4.y += v.y; d4.z += v.z; d4.w += v.w;
        }
        int s = d4.x + d4.y + d4.z + d4.w;
        aux[t] = s;
        __syncthreads();
        for (int off = 1; off < 1024; off <<= 1) {
            int v = (t >= off) ? aux[t - off] : 0;
            __syncthreads();
            aux[t] += v;
            __syncthreads();
        }
        int run = (t > 0) ? aux[t - 1] : 0;
        int d[4] = {d4.x, d4.y, d4.z, d4.w};
#pragma unroll
        for (int i = 0; i < 4; i++) {
            int idx = t * 4 + i;
            row_ptr[idx] = run;
            cursor[idx] = run;
            dinv[idx] = rsqrtf((float)(d[i] + 1));  // +1: self loop
            run += d[i];
        }
        if (t == 1023) row_ptr[NN] = run;
    } else {
        // ---- xw1_partial = x @ W1p (32 rows per block) ----
        __shared__ float xt[32 * NDD];
        int r0 = (b - (GG + 1)) * 32;
        if (t < 512) xt[t] = x[r0 * NDD + t];
        __syncthreads();
        int col = t & 127, rh = t >> 7;  // rh 0..7
        float acc[4] = {0.f, 0.f, 0.f, 0.f};
#pragma unroll
        for (int k = 0; k < NDD; k++) {
            float w = W1p[k * HH + col];
#pragma unroll
            for (int i = 0; i < 4; i++) acc[i] += xt[(rh * 4 + i) * NDD + k] * w;
        }
#pragma unroll
        for (int i = 0; i < 4; i++) xw[(r0 + rh * 4 + i) * HH + col] = acc[i];
    }
}

// ============ K3: scatter int4 (0..127) + xw1 fixup (+c1[bm])*dinv (128..639) ============
__global__ __launch_bounds__(256) void k_scatfix(
    const int* __restrict__ e_src, const int* __restrict__ e_dst,
    int* __restrict__ cursor, int* __restrict__ col_idx,
    const float* __restrict__ c1, const int* __restrict__ bm,
    const float* __restrict__ dinv, float* __restrict__ xw) {
    int b = blockIdx.x, t = threadIdx.x;
    if (b < 128) {
        int i4 = b * 256 + t;
        int4 d4 = ((const int4*)e_dst)[i4];
        int4 s4 = ((const int4*)e_src)[i4];
        int p;
        p = atomicAdd(&cursor[d4.x], 1); col_idx[p] = s4.x;
        p = atomicAdd(&cursor[d4.y], 1); col_idx[p] = s4.y;
        p = atomicAdd(&cursor[d4.z], 1); col_idx[p] = s4.z;
        p = atomicAdd(&cursor[d4.w], 1); col_idx[p] = s4.w;
        return;
    }
    int r0 = (b - 128) * 8;
    int col = t & 127, rh = t >> 7;
#pragma unroll
    for (int i = 0; i < 4; i++) {
        int row = r0 + rh * 4 + i;
        xw[row * HH + col] = (xw[row * HH + col] + c1[bm[row] * HH + col]) * dinv[row];
    }
}

// ============ K4: conv1 aggregate + fused gemm2 (Wc2 staged in LDS). One wave per dst. ============
__global__ __launch_bounds__(256) void k_conv1(
    const float* __restrict__ xw, const int* __restrict__ row_ptr,
    const int* __restrict__ col_idx, const float* __restrict__ dinv,
    const float* __restrict__ b1, const float* __restrict__ Wc2,
    float* __restrict__ xw2) {
    int w = threadIdx.x >> 6, l = threadIdx.x & 63;
    int dst = blockIdx.x * 4 + w;
    const float2* xwp = (const float2*)xw;
    float2 acc = xwp[dst * 64 + l];  // self loop, pre-scaled
    int beg = row_ptr[dst], end = row_ptr[dst + 1];
    int e = beg;
    for (; e + 7 < end; e += 8) {
        int s0 = col_idx[e], s1 = col_idx[e + 1], s2 = col_idx[e + 2], s3 = col_idx[e + 3];
        int s4 = col_idx[e + 4], s5 = col_idx[e + 5], s6 = col_idx[e + 6], s7 = col_idx[e + 7];
        float2 v0 = xwp[s0 * 64 + l], v1 = xwp[s1 * 64 + l];
        float2 v2 = xwp[s2 * 64 + l], v3 = xwp[s3 * 64 + l];
        float2 v4 = xwp[s4 * 64 + l], v5 = xwp[s5 * 64 + l];
        float2 v6 = xwp[s6 * 64 + l], v7 = xwp[s7 * 64 + l];
        acc.x += ((v0.x + v1.x) + (v2.x + v3.x)) + ((v4.x + v5.x) + (v6.x + v7.x));
        acc.y += ((v0.y + v1.y) + (v2.y + v3.y)) + ((v4.y + v5.y) + (v6.y + v7.y));
    }
    for (; e + 3 < end; e += 4) {
        int s0 = col_idx[e], s1 = col_idx[e + 1], s2 = col_idx[e + 2], s3 = col_idx[e + 3];
        float2 v0 = xwp[s0 * 64 + l], v1 = xwp[s1 * 64 + l];
        float2 v2 = xwp[s2 * 64 + l], v3 = xwp[s3 * 64 + l];
        acc.x += (v0.x + v1.x) + (v2.x + v3.x);
        acc.y += (v0.y + v1.y) + (v2.y + v3.y);
    }
    for (; e < end; e++) {
        float2 v = xwp[col_idx[e] * 64 + l];
        acc.x += v.x;
        acc.y += v.y;
    }
    float dd = dinv[dst];
    float2 h;
    h.x = fmaxf(dd * acc.x + b1[2 * l], 0.f);
    h.y = fmaxf(dd * acc.y + b1[2 * l + 1], 0.f);
    __shared__ float hr[4][HH];
    __shared__ float wsm[64 * HH];  // 32 KB: half of Wc2 at a time
    *(float2*)&hr[w][2 * l] = h;
    float2 o = {0.f, 0.f};
#pragma unroll
    for (int half = 0; half < 2; half++) {
        __syncthreads();  // hr ready (half 0) / previous half's reads done (half 1)
        const float4* src4 = (const float4*)(Wc2 + half * 64 * HH);
        float4* dst4 = (float4*)wsm;
#pragma unroll
        for (int i = 0; i < (64 * HH / 4) / 256; i++)
            dst4[i * 256 + threadIdx.x] = src4[i * 256 + threadIdx.x];
        __syncthreads();
#pragma unroll 4
        for (int k = 0; k < 64; k++) {
            float hk = hr[w][half * 64 + k];
            float2 wv = *(const float2*)&wsm[k * HH + 2 * l];
            o.x += hk * wv.x;
            o.y += hk * wv.y;
        }
    }
    o.x *= dd;
    o.y *= dd;
    ((float2*)xw2)[dst * 64 + l] = o;
}

// ============ K5: conv2 aggregate + pred + sl/sr. One wave per dst row. ============
__global__ __launch_bounds__(256) void k_conv2_head(
    const float* __restrict__ xw, const int* __restrict__ row_ptr,
    const int* __restrict__ col_idx, const float* __restrict__ dinv,
    const float* __restrict__ b2, const float* __restrict__ Wo,
    const float* __restrict__ bo, const float* __restrict__ we,
    float* __restrict__ out_pred, float* __restrict__ sl, float* __restrict__ sr) {
    int w = threadIdx.x >> 6, l = threadIdx.x & 63;
    int dst = blockIdx.x * 4 + w;
    const float2* xwp = (const float2*)xw;
    float2 acc = xwp[dst * 64 + l];
    int beg = row_ptr[dst], end = row_ptr[dst + 1];
    int e = beg;
    for (; e + 7 < end; e += 8) {
        int s0 = col_idx[e], s1 = col_idx[e + 1], s2 = col_idx[e + 2], s3 = col_idx[e + 3];
        int s4 = col_idx[e + 4], s5 = col_idx[e + 5], s6 = col_idx[e + 6], s7 = col_idx[e + 7];
        float2 v0 = xwp[s0 * 64 + l], v1 = xwp[s1 * 64 + l];
        float2 v2 = xwp[s2 * 64 + l], v3 = xwp[s3 * 64 + l];
        float2 v4 = xwp[s4 * 64 + l], v5 = xwp[s5 * 64 + l];
        float2 v6 = xwp[s6 * 64 + l], v7 = xwp[s7 * 64 + l];
        acc.x += ((v0.x + v1.x) + (v2.x + v3.x)) + ((v4.x + v5.x) + (v6.x + v7.x));
        acc.y += ((v0.y + v1.y) + (v2.y + v3.y)) + ((v4.y + v5.y) + (v6.y + v7.y));
    }
    for (; e + 3 < end; e += 4) {
        int s0 = col_idx[e], s1 = col_idx[e + 1], s2 = col_idx[e + 2], s3 = col_idx[e + 3];
        float2 v0 = xwp[s0 * 64 + l], v1 = xwp[s1 * 64 + l];
        float2 v2 = xwp[s2 * 64 + l], v3 = xwp[s3 * 64 + l];
        acc.x += (v0.x + v1.x) + (v2.x + v3.x);
        acc.y += (v0.y + v1.y) + (v2.y + v3.y);
    }
    for (; e < end; e++) {
        float2 v = xwp[col_idx[e] * 64 + l];
        acc.x += v.x;
        acc.y += v.y;
    }
    float dd = dinv[dst];
    float2 h;
    h.x = fmaxf(dd * acc.x + b2[2 * l], 0.f);
    h.y = fmaxf(dd * acc.y + b2[2 * l + 1], 0.f);
    __shared__ float hr[4][HH];
    *(float2*)&hr[w][2 * l] = h;
    __syncthreads();
    // pred: c = l&15, partial p = l>>4 over k in [32p, 32p+32)
    {
        int c = l & 15, p = l >> 4;
        float a = 0.f;
#pragma unroll 4
        for (int k = p * 32; k < p * 32 + 32; k++) a += hr[w][k] * Wo[k * NDD + c];
        a += __shfl_xor(a, 16);
        a += __shfl_xor(a, 32);
        if (p == 0) out_pred[dst * NDD + c] = a + bo[c];
    }
    // sl/sr
    {
        float h0 = hr[w][l], h1v = hr[w][64 + l];
        float pl = h0 * we[l] + h1v * we[64 + l];
        float pr = h0 * we[HH + l] + h1v * we[HH + 64 + l];
        for (int off = 32; off; off >>= 1) {
            pl += __shfl_down(pl, off);
            pr += __shfl_down(pr, off);
        }
        if (l == 0) {
            sl[dst] = pl;
            sr[dst] = pr;
        }
    }
}

// ============ K6: edge logits, nontemporal stores, rows b and NN-2-b per block ============
__global__ __launch_bounds__(256) void k_edges(const float* __restrict__ sl,
                                               const float* __restrict__ sr,
                                               const float* __restrict__ be_p,
                                               float* __restrict__ out) {
    int b = blockIdx.x, t = threadIdx.x;
    float be = be_p[0];
#pragma unroll
    for (int half = 0; half < 2; half++) {
        int r = half == 0 ? b : (NN - 2 - b);
        int off = r * (2 * NN - r - 1) / 2;  // < 2^23, fits int
        int len = NN - 1 - r;
        float s = sl[r] + be;
        const float* sp = sr + r + 1;
        float* op = out + off;
        int hd = (4 - (off & 3)) & 3;
        if (hd > len) hd = len;
        if (t < hd) __builtin_nontemporal_store(s + sp[t], op + t);
        int body = (len - hd) >> 2;
        float* opb = op + hd;
        const float* spb = sp + hd;
        for (int i = t; i < body; i += 256) {
            int base = 4 * i;
            nt_f4 v;
            v.x = s + spb[base];
            v.y = s + spb[base + 1];
            v.z = s + spb[base + 2];
            v.w = s + spb[base + 3];
            __builtin_nontemporal_store(v, (nt_f4*)(opb + base));
        }
        int tail = hd + body * 4;
        int rem = len - tail;
        if (t < rem) __builtin_nontemporal_store(s + sp[tail + t], op + tail + t);
    }
}

extern "C" void kernel_launch(void* const* d_in, const int* in_sizes, int n_in,
                              void* d_out, int out_size, void* d_ws, size_t ws_size,
                              hipStream_t stream) {
    const float* x = (const float*)d_in[0];
    const int* e_src = (const int*)d_in[1];
    const int* e_dst = e_src + EE;
    const int* timestep = (const int*)d_in[2];
    const int* batch_map = (const int*)d_in[3];
    const int* nuc = (const int*)d_in[4];
    const int* central = (const int*)d_in[5];
    const int* backbone = (const int*)d_in[6];
    const float* obj_x = (const float*)d_in[7];
    const float* obj_pos = (const float*)d_in[8];
    const int* obj_batch = (const int*)d_in[9];
    const float* W_node = (const float*)d_in[10];
    const float* b_node = (const float*)d_in[11];
    const float* W_cond = (const float*)d_in[12];
    const float* b_cond = (const float*)d_in[13];
    const float* W_time = (const float*)d_in[14];
    const float* b_time = (const float*)d_in[15];
    const float* W_conv1 = (const float*)d_in[16];
    const float* b_conv1 = (const float*)d_in[17];
    const float* W_conv2 = (const float*)d_in[18];
    const float* b_conv2 = (const float*)d_in[19];
    const float* W_out = (const float*)d_in[20];
    const float* b_out = (const float*)d_in[21];
    const float* w_edge = (const float*)d_in[22];
    const float* b_edge = (const float*)d_in[23];

    // workspace
    float* ws = (float*)d_ws;
    float* bufA = ws;                        // N*H (xw1')
    float* bufB = bufA + NN * HH;            // N*H (xw2')
    float* W1p = bufB + NN * HH;             // 16*H
    float* c1 = W1p + NDD * HH;              // G*H
    float* partial = c1 + GG * HH;           // CBLK*G*16
    float* pcnt = partial + CBLK * GG * NDD; // CBLK*G
    float* dinv = pcnt + CBLK * GG;          // N
    float* sl = dinv + NN;                   // N
    float* sr = sl + NN;                     // N
    int* phist = (int*)(sr + NN);            // HBLK*N
    int* row_ptr = phist + HBLK * NN;        // N+1
    int* cursor = row_ptr + NN + 1;          // N
    int* col_idx = cursor + NN;              // E

    float* out_pred = (float*)d_out;
    float* out_edges = out_pred + NN * NDD;

    // K1: cond partials + deg histograms + W1p  (no memset needed)
    k_front<<<CBLK + HBLK + WBLK, 256, 0, stream>>>(obj_x, obj_pos, nuc, central,
                                                    backbone, obj_batch, e_dst, phist,
                                                    partial, pcnt, W_node, W_conv1, W1p);
    // K2: c1 (8 blocks) + scan + xw1_partial
    k_mid<<<GG + 1 + NN / 32, 1024, 0, stream>>>(timestep, partial, pcnt, W_node,
                                                 b_node, W_time, b_time, W_cond, b_cond,
                                                 W_conv1, c1, phist, row_ptr, cursor,
                                                 dinv, x, W1p, bufA);
    // K3: scatter + fixup
    k_scatfix<<<128 + 512, 256, 0, stream>>>(e_src, e_dst, cursor, col_idx, c1,
                                             batch_map, dinv, bufA);
    // K4: conv1 agg + gemm2 -> xw2'
    k_conv1<<<NN / 4, 256, 0, stream>>>(bufA, row_ptr, col_idx, dinv, b_conv1,
                                        W_conv2, bufB);
    // K5: conv2 agg + pred + sl/sr
    k_conv2_head<<<NN / 4, 256, 0, stream>>>(bufB, row_ptr, col_idx, dinv, b_conv2,
                                             W_out, b_out, w_edge, out_pred, sl, sr);
    // K6: edge logits
    k_edges<<<NN / 2, 256, 0, stream>>>(sl, sr, b_edge, out_edges);
}